// Round 2
// baseline (1638.638 us; speedup 1.0000x reference)
//
#include <hip/hip_runtime.h>
#include <hip/hip_bf16.h>
#include <float.h>
#include <math.h>

#define BATCH 16
#define NPTS  4096
#define CIN   64
#define MCENT 1024
#define KNB   32
#define OUT_X (BATCH * MCENT * 128)

// ---- exact (non-contracted) f32 ops: bitwise-match numpy's separate roundings ----
__device__ __forceinline__ float f_sub(float a, float b){ float r; asm("v_sub_f32 %0, %1, %2" : "=v"(r) : "v"(a), "v"(b)); return r; }
__device__ __forceinline__ float f_mul(float a, float b){ float r; asm("v_mul_f32 %0, %1, %2" : "=v"(r) : "v"(a), "v"(b)); return r; }
__device__ __forceinline__ float f_add(float a, float b){ float r; asm("v_add_f32 %0, %1, %2" : "=v"(r) : "v"(a), "v"(b)); return r; }

__device__ __forceinline__ float dist2_exact(float px, float py, float pz,
                                             float lx, float ly, float lz) {
    float dx = f_sub(px, lx), dy = f_sub(py, ly), dz = f_sub(pz, lz);
    return f_add(f_add(f_mul(dx, dx), f_mul(dy, dy)), f_mul(dz, dz));
}

// ================= K1: farthest point sampling =================
// one block per batch; 1024 threads; each thread owns 4 points in registers.
__global__ __launch_bounds__(1024, 1) void fps_kernel(
    const float* __restrict__ pos, float* __restrict__ cpos)
{
    __shared__ float spx[NPTS], spy[NPTS], spz[NPTS];
    __shared__ unsigned long long pairbuf[2][16];
    __shared__ int widx[MCENT];

    const int b = blockIdx.x;
    const int t = threadIdx.x;
    const float* pb = pos + (size_t)b * NPTS * 3;

    float px[4], py[4], pz[4], mind[4];
    int pid[4];
#pragma unroll
    for (int j = 0; j < 4; ++j) {
        int n = t + j * 1024;
        pid[j] = n;
        px[j] = pb[n * 3 + 0];
        py[j] = pb[n * 3 + 1];
        pz[j] = pb[n * 3 + 2];
        spx[n] = px[j]; spy[n] = py[j]; spz[n] = pz[j];
        mind[j] = 1e10f;
    }
    if (t == 0) widx[0] = 0;
    __syncthreads();

    const int lane = t & 63, wave = t >> 6;
    int w = 0;
    for (int i = 1; i < MCENT; ++i) {
        float lx = spx[w], ly = spy[w], lz = spz[w];
        unsigned long long best = 0ull;
#pragma unroll
        for (int j = 0; j < 4; ++j) {
            float d = dist2_exact(px[j], py[j], pz[j], lx, ly, lz);
            mind[j] = fminf(mind[j], d);
            // key: larger dist wins; tie -> smaller index wins (argmax-first semantics)
            unsigned long long key =
                ((unsigned long long)__float_as_uint(mind[j]) << 32) |
                (unsigned)(NPTS - 1 - pid[j]);
            best = best > key ? best : key;
        }
#pragma unroll
        for (int m = 1; m < 64; m <<= 1) {
            unsigned long long o = __shfl_xor(best, m);
            best = best > o ? best : o;
        }
        if (lane == 0) pairbuf[i & 1][wave] = best;
        __syncthreads();
#pragma unroll
        for (int q = 0; q < 16; ++q) {
            unsigned long long o = pairbuf[i & 1][q];
            best = best > o ? best : o;
        }
        w = (NPTS - 1) - (int)(unsigned)(best & 0xFFFFFFFFull);
        if (t == 0) widx[i] = w;
    }
    __syncthreads();
    // emit centroid positions (bitwise copies of pos)
    int src = widx[t];
    float* cp = cpos + ((size_t)b * MCENT + t) * 3;
    cp[0] = spx[src]; cp[1] = spy[src]; cp[2] = spz[src];
}

// ================= K2: ball query (first K in index order within radius) =================
// one wave per centroid.
__global__ __launch_bounds__(256) void ballq_kernel(
    const float* __restrict__ pos, const float* __restrict__ cpos,
    int* __restrict__ nidx)
{
    const int wid  = blockIdx.x * 4 + (threadIdx.x >> 6);  // centroid id 0..B*M-1
    const int lane = threadIdx.x & 63;
    const int b    = wid >> 10;
    const float* pb = pos + (size_t)b * NPTS * 3;
    const float cx = cpos[wid * 3 + 0];
    const float cy = cpos[wid * 3 + 1];
    const float cz = cpos[wid * 3 + 2];
    const float R2 = (float)(0.2 * 0.2);   // 0x3D23D70A — equivalent predicate to reference
    int* outp = nidx + (size_t)wid * KNB;

    int cnt = 0;
    for (int j0 = 0; j0 < NPTS; j0 += 64) {
        int j = j0 + lane;
        float x = pb[j * 3 + 0], y = pb[j * 3 + 1], z = pb[j * 3 + 2];
        float d = dist2_exact(x, y, z, cx, cy, cz);
        bool valid = (d <= R2);
        unsigned long long msk = __ballot(valid);
        if (valid) {
            int rank = cnt + __popcll(msk & ((1ull << lane) - 1ull));
            if (rank < KNB) outp[rank] = j;
        }
        cnt += __popcll(msk);
        if (cnt >= KNB) break;
    }
    int nv = cnt < KNB ? cnt : KNB;
    if (lane >= nv && lane < KNB) outp[lane] = -1;
}

// ================= K3: gather + shared MLP + masked max-pool =================
// 256 threads = 8 centroids x 32 neighbor-rows; one row per thread.
__global__ __launch_bounds__(256, 1) void mlp_kernel(
    const float* __restrict__ x, const float* __restrict__ pos,
    const float* __restrict__ W1, const float* __restrict__ g1, const float* __restrict__ b1,
    const float* __restrict__ rm1, const float* __restrict__ rv1,
    const float* __restrict__ W2, const float* __restrict__ g2, const float* __restrict__ b2,
    const float* __restrict__ rm2, const float* __restrict__ rv2,
    const float* __restrict__ W3, const float* __restrict__ g3, const float* __restrict__ b3,
    const float* __restrict__ rm3, const float* __restrict__ rv3,
    const float* __restrict__ cpos, const int* __restrict__ nidx,
    float* __restrict__ out)
{
    __shared__ float hbuf[256 * 69];      // per-thread activation row (LDS, stride 69: conflict-free)
    __shared__ float sscale[256], sbias[256];

    const int t   = threadIdx.x;
    const int g   = t >> 5;               // centroid within block
    const int k   = t & 31;               // neighbor slot
    const int cid0 = blockIdx.x * 8;
    const int cid  = cid0 + g;
    const int b    = cid >> 10;

    // fused BN(eval) constants: y = h*scale + bias
    {
        float gg, bb, rm, rv;
        if (t < 64)       { gg = g1[t];     bb = b1[t];     rm = rm1[t];     rv = rv1[t]; }
        else if (t < 128) { int c = t - 64;  gg = g2[c]; bb = b2[c]; rm = rm2[c]; rv = rv2[c]; }
        else              { int c = t - 128; gg = g3[c]; bb = b3[c]; rm = rm3[c]; rv = rv3[c]; }
        float s = gg / sqrtf(rv + 1e-5f);
        sscale[t] = s;
        sbias[t]  = bb - rm * s;
    }

    const int j = nidx[(size_t)cid * KNB + k];
    const bool valid = (j >= 0);
    float* hrow = &hbuf[t * 69];
    if (valid) {
        const float* xr = x + ((size_t)b * NPTS + j) * CIN;
#pragma unroll
        for (int q = 0; q < 16; ++q) {
            float4 v = ((const float4*)xr)[q];
            hrow[q * 4 + 0] = v.x; hrow[q * 4 + 1] = v.y;
            hrow[q * 4 + 2] = v.z; hrow[q * 4 + 3] = v.w;
        }
        const float* pr = pos + ((size_t)b * NPTS + j) * 3;
        hrow[64] = f_sub(pr[0], cpos[cid * 3 + 0]);
        hrow[65] = f_sub(pr[1], cpos[cid * 3 + 1]);
        hrow[66] = f_sub(pr[2], cpos[cid * 3 + 2]);
    } else {
        for (int q = 0; q < 67; ++q) hrow[q] = 0.f;
    }
    __syncthreads();   // sscale/sbias ready

    float acc[64];
    // ---- layer 1: 67 -> 64 ----
#pragma unroll
    for (int c = 0; c < 64; ++c) acc[c] = 0.f;
#pragma unroll 2
    for (int kk = 0; kk < 67; ++kk) {
        float hv = hrow[kk];
        const float* wr = W1 + kk * 64;     // wave-uniform -> scalar loads
#pragma unroll
        for (int c = 0; c < 64; ++c) acc[c] = fmaf(hv, wr[c], acc[c]);
    }
#pragma unroll
    for (int c = 0; c < 64; ++c)
        hrow[c] = fmaxf(fmaf(acc[c], sscale[c], sbias[c]), 0.f);

    // ---- layer 2: 64 -> 64 ----
#pragma unroll
    for (int c = 0; c < 64; ++c) acc[c] = 0.f;
#pragma unroll 2
    for (int kk = 0; kk < 64; ++kk) {
        float hv = hrow[kk];
        const float* wr = W2 + kk * 64;
#pragma unroll
        for (int c = 0; c < 64; ++c) acc[c] = fmaf(hv, wr[c], acc[c]);
    }
#pragma unroll
    for (int c = 0; c < 64; ++c)
        hrow[c] = fmaxf(fmaf(acc[c], sscale[64 + c], sbias[64 + c]), 0.f);

    // ---- layer 3: 64 -> 128 ----
    float acc3[128];
#pragma unroll
    for (int c = 0; c < 128; ++c) acc3[c] = 0.f;
#pragma unroll 2
    for (int kk = 0; kk < 64; ++kk) {
        float hv = hrow[kk];
        const float* wr = W3 + kk * 128;
#pragma unroll
        for (int c = 0; c < 128; ++c) acc3[c] = fmaf(hv, wr[c], acc3[c]);
    }
#pragma unroll
    for (int c = 0; c < 128; ++c) {
        float v = fmaxf(fmaf(acc3[c], sscale[128 + c], sbias[128 + c]), 0.f);
        acc3[c] = valid ? v : -FLT_MAX;
    }

    // ---- masked max over 32 neighbors, two 64-channel halves (reuse hbuf) ----
#pragma unroll
    for (int half = 0; half < 2; ++half) {
        __syncthreads();   // previous hbuf readers done
#pragma unroll
        for (int c = 0; c < 64; ++c) hbuf[t * 69 + c] = acc3[half * 64 + c];
        __syncthreads();
#pragma unroll
        for (int e0 = 0; e0 < 2; ++e0) {
            int e  = t + e0 * 256;          // 512 outputs per half
            int gg = e >> 6, c = e & 63;
            float mv = -FLT_MAX;
#pragma unroll
            for (int kk2 = 0; kk2 < 32; ++kk2)
                mv = fmaxf(mv, hbuf[(gg * 32 + kk2) * 69 + c]);
            out[((size_t)(cid0 + gg)) * 128 + half * 64 + c] = mv;
        }
    }
}

extern "C" void kernel_launch(void* const* d_in, const int* in_sizes, int n_in,
                              void* d_out, int out_size, void* d_ws, size_t ws_size,
                              hipStream_t stream) {
    const float* x   = (const float*)d_in[0];
    const float* pos = (const float*)d_in[1];
    const float* W1  = (const float*)d_in[2];
    const float* g1  = (const float*)d_in[3];
    const float* b1  = (const float*)d_in[4];
    const float* rm1 = (const float*)d_in[5];
    const float* rv1 = (const float*)d_in[6];
    const float* W2  = (const float*)d_in[7];
    const float* g2  = (const float*)d_in[8];
    const float* b2  = (const float*)d_in[9];
    const float* rm2 = (const float*)d_in[10];
    const float* rv2 = (const float*)d_in[11];
    const float* W3  = (const float*)d_in[12];
    const float* g3  = (const float*)d_in[13];
    const float* b3  = (const float*)d_in[14];
    const float* rm3 = (const float*)d_in[15];
    const float* rv3 = (const float*)d_in[16];

    float* out  = (float*)d_out;
    float* cpos = out + OUT_X;          // second output region
    int*   nidx = (int*)d_ws;           // B*M*K ints = 2 MiB scratch

    fps_kernel<<<dim3(BATCH), dim3(1024), 0, stream>>>(pos, cpos);
    ballq_kernel<<<dim3(BATCH * MCENT / 4), dim3(256), 0, stream>>>(pos, cpos, nidx);
    mlp_kernel<<<dim3(BATCH * MCENT / 8), dim3(256), 0, stream>>>(
        x, pos, W1, g1, b1, rm1, rv1, W2, g2, b2, rm2, rv2,
        W3, g3, b3, rm3, rv3, cpos, nidx, out);
}

// Round 5
// 1174.465 us; speedup vs baseline: 1.3952x; 1.3952x over previous
//
#include <hip/hip_runtime.h>
#include <hip/hip_bf16.h>
#include <float.h>
#include <math.h>

#define BATCH 16
#define NPTS  4096
#define CIN   64
#define MCENT 1024
#define KNB   32
#define OUT_X (BATCH * MCENT * 128)

// ---- exact (non-contracted) f32 ops: bitwise-match numpy's separate roundings ----
__device__ __forceinline__ float f_sub(float a, float b){ float r; asm("v_sub_f32 %0, %1, %2" : "=v"(r) : "v"(a), "v"(b)); return r; }
__device__ __forceinline__ float f_mul(float a, float b){ float r; asm("v_mul_f32 %0, %1, %2" : "=v"(r) : "v"(a), "v"(b)); return r; }
__device__ __forceinline__ float f_add(float a, float b){ float r; asm("v_add_f32 %0, %1, %2" : "=v"(r) : "v"(a), "v"(b)); return r; }

__device__ __forceinline__ float dist2_exact(float px, float py, float pz,
                                             float lx, float ly, float lz) {
    float dx = f_sub(px, lx), dy = f_sub(py, ly), dz = f_sub(pz, lz);
    return f_add(f_add(f_mul(dx, dx), f_mul(dy, dy)), f_mul(dz, dz));
}

// fast wave-wide f32 max: 4 DPP steps + xor16 swizzle + xor32 shuffle
template <int CTRL>
__device__ __forceinline__ float dpp_max(float x) {
    int xi = __float_as_int(x);
    int yi = __builtin_amdgcn_update_dpp(xi, xi, CTRL, 0xF, 0xF, false);
    return fmaxf(x, __int_as_float(yi));
}
__device__ __forceinline__ float wave_max_f32(float v) {
    v = dpp_max<0xB1>(v);   // quad_perm [1,0,3,2]  : xor 1
    v = dpp_max<0x4E>(v);   // quad_perm [2,3,0,1]  : xor 2
    v = dpp_max<0x141>(v);  // row_half_mirror      : xor 4 (8-group merge)
    v = dpp_max<0x140>(v);  // row_mirror           : xor 8 (16-group merge)
    int s = __builtin_amdgcn_ds_swizzle(__float_as_int(v), 0x401F); // xor 16
    v = fmaxf(v, __int_as_float(s));
    v = fmaxf(v, __shfl_xor(v, 32));
    return v;
}

// ================= K1: farthest point sampling =================
// one block per batch; 512 threads (8 waves); each thread owns 8 contiguous points.
__global__ __launch_bounds__(512, 1) void fps_kernel(
    const float* __restrict__ pos, float* __restrict__ cpos)
{
    __shared__ float spx[NPTS], spy[NPTS], spz[NPTS];
    __shared__ __align__(16) float swmax[8];
    __shared__ int widxslot[2];
    __shared__ int widxarr[MCENT];

    const int b = blockIdx.x;
    const int t = threadIdx.x;
    const float* pb = pos + (size_t)b * NPTS * 3;

    float px[8], py[8], pz[8], mind[8];
    // contiguous 8 points: 6 x float4 = 96B per thread, coalesced across block
    {
        const float4* src = (const float4*)(pb + t * 24);
        float v[24];
#pragma unroll
        for (int q = 0; q < 6; ++q) {
            float4 f = src[q];
            v[q * 4 + 0] = f.x; v[q * 4 + 1] = f.y; v[q * 4 + 2] = f.z; v[q * 4 + 3] = f.w;
        }
#pragma unroll
        for (int j = 0; j < 8; ++j) {
            int n = t * 8 + j;
            px[j] = v[j * 3 + 0]; py[j] = v[j * 3 + 1]; pz[j] = v[j * 3 + 2];
            spx[n] = px[j]; spy[n] = py[j]; spz[n] = pz[j];
            mind[j] = 1e10f;
        }
    }
    if (t == 0) { widxslot[0] = 0x7FFFFFFF; widxslot[1] = 0x7FFFFFFF; widxarr[0] = 0; }
    __syncthreads();

    int w = 0;
    for (int i = 1; i < MCENT; ++i) {
        float lx = spx[w], ly = spy[w], lz = spz[w];
        float tmax = -1.0f;
#pragma unroll
        for (int j = 0; j < 8; ++j) {
            float d = dist2_exact(px[j], py[j], pz[j], lx, ly, lz);
            mind[j] = fminf(mind[j], d);
            tmax = fmaxf(tmax, mind[j]);
        }
        float wmax = wave_max_f32(tmax);
        if ((t & 63) == 0) swmax[t >> 6] = wmax;
        __syncthreads();                       // A: swmax ready
        float4 m0 = *(const float4*)&swmax[0];
        float4 m1 = *(const float4*)&swmax[4];
        float gmax = fmaxf(fmaxf(fmaxf(m0.x, m0.y), fmaxf(m0.z, m0.w)),
                           fmaxf(fmaxf(m1.x, m1.y), fmaxf(m1.z, m1.w)));
        if (t == 0) widxslot[(i + 1) & 1] = 0x7FFFFFFF;   // reset other slot (safe: A..B window)
        if (tmax == gmax) {                    // rare: ~1 thread
            int cand = 0x7FFFFFFF;
#pragma unroll
            for (int j = 7; j >= 0; --j)
                if (mind[j] == gmax) cand = t * 8 + j;    // ends at smallest matching j
            atomicMin(&widxslot[i & 1], cand);
        }
        __syncthreads();                       // B: winner ready
        w = widxslot[i & 1];
        if (t == 0) widxarr[i] = w;
    }
    __syncthreads();
    // emit centroid positions (bitwise copies of pos); 2 per thread
#pragma unroll
    for (int e = 0; e < 2; ++e) {
        int c = t + e * 512;
        int src = widxarr[c];
        float* cp = cpos + ((size_t)b * MCENT + c) * 3;
        cp[0] = spx[src]; cp[1] = spy[src]; cp[2] = spz[src];
    }
}

// ================= K2: ball query (first K in index order within radius) =================
// one wave per centroid.
__global__ __launch_bounds__(256) void ballq_kernel(
    const float* __restrict__ pos, const float* __restrict__ cpos,
    int* __restrict__ nidx)
{
    const int wid  = blockIdx.x * 4 + (threadIdx.x >> 6);  // centroid id 0..B*M-1
    const int lane = threadIdx.x & 63;
    const int b    = wid >> 10;
    const float* pb = pos + (size_t)b * NPTS * 3;
    const float cx = cpos[wid * 3 + 0];
    const float cy = cpos[wid * 3 + 1];
    const float cz = cpos[wid * 3 + 2];
    const float R2 = (float)(0.2 * 0.2);   // 0x3D23D70A — equivalent predicate to reference
    int* outp = nidx + (size_t)wid * KNB;

    int cnt = 0;
    for (int j0 = 0; j0 < NPTS; j0 += 64) {
        int j = j0 + lane;
        float x = pb[j * 3 + 0], y = pb[j * 3 + 1], z = pb[j * 3 + 2];
        float d = dist2_exact(x, y, z, cx, cy, cz);
        bool valid = (d <= R2);
        unsigned long long msk = __ballot(valid);
        if (valid) {
            int rank = cnt + __popcll(msk & ((1ull << lane) - 1ull));
            if (rank < KNB) outp[rank] = j;
        }
        cnt += __popcll(msk);
        if (cnt >= KNB) break;
    }
    int nv = cnt < KNB ? cnt : KNB;
    if (lane >= nv && lane < KNB) outp[lane] = -1;
}

// ================= K3: gather + shared MLP + masked max-pool =================
// 256 threads = 8 centroids x 32 neighbor-rows; one row per thread.
__global__ __launch_bounds__(256, 1) void mlp_kernel(
    const float* __restrict__ x, const float* __restrict__ pos,
    const float* __restrict__ W1, const float* __restrict__ g1, const float* __restrict__ b1,
    const float* __restrict__ rm1, const float* __restrict__ rv1,
    const float* __restrict__ W2, const float* __restrict__ g2, const float* __restrict__ b2,
    const float* __restrict__ rm2, const float* __restrict__ rv2,
    const float* __restrict__ W3, const float* __restrict__ g3, const float* __restrict__ b3,
    const float* __restrict__ rm3, const float* __restrict__ rv3,
    const float* __restrict__ cpos, const int* __restrict__ nidx,
    float* __restrict__ out)
{
    __shared__ float hbuf[256 * 69];      // per-thread activation row (LDS, stride 69: conflict-free)
    __shared__ float sscale[256], sbias[256];

    const int t   = threadIdx.x;
    const int g   = t >> 5;               // centroid within block
    const int k   = t & 31;               // neighbor slot
    const int cid0 = blockIdx.x * 8;
    const int cid  = cid0 + g;
    const int b    = cid >> 10;

    // fused BN(eval) constants: y = h*scale + bias
    {
        float gg, bb, rm, rv;
        if (t < 64)       { gg = g1[t];     bb = b1[t];     rm = rm1[t];     rv = rv1[t]; }
        else if (t < 128) { int c = t - 64;  gg = g2[c]; bb = b2[c]; rm = rm2[c]; rv = rv2[c]; }
        else              { int c = t - 128; gg = g3[c]; bb = b3[c]; rm = rm3[c]; rv = rv3[c]; }
        float s = gg / sqrtf(rv + 1e-5f);
        sscale[t] = s;
        sbias[t]  = bb - rm * s;
    }

    const int j = nidx[(size_t)cid * KNB + k];
    const bool valid = (j >= 0);
    float* hrow = &hbuf[t * 69];
    if (valid) {
        const float* xr = x + ((size_t)b * NPTS + j) * CIN;
#pragma unroll
        for (int q = 0; q < 16; ++q) {
            float4 v = ((const float4*)xr)[q];
            hrow[q * 4 + 0] = v.x; hrow[q * 4 + 1] = v.y;
            hrow[q * 4 + 2] = v.z; hrow[q * 4 + 3] = v.w;
        }
        const float* pr = pos + ((size_t)b * NPTS + j) * 3;
        hrow[64] = f_sub(pr[0], cpos[cid * 3 + 0]);
        hrow[65] = f_sub(pr[1], cpos[cid * 3 + 1]);
        hrow[66] = f_sub(pr[2], cpos[cid * 3 + 2]);
    } else {
        for (int q = 0; q < 67; ++q) hrow[q] = 0.f;
    }
    __syncthreads();   // sscale/sbias ready

    float acc[64];
    // ---- layer 1: 67 -> 64 ----
#pragma unroll
    for (int c = 0; c < 64; ++c) acc[c] = 0.f;
#pragma unroll 2
    for (int kk = 0; kk < 67; ++kk) {
        float hv = hrow[kk];
        const float* wr = W1 + kk * 64;     // wave-uniform -> scalar loads
#pragma unroll
        for (int c = 0; c < 64; ++c) acc[c] = fmaf(hv, wr[c], acc[c]);
    }
#pragma unroll
    for (int c = 0; c < 64; ++c)
        hrow[c] = fmaxf(fmaf(acc[c], sscale[c], sbias[c]), 0.f);

    // ---- layer 2: 64 -> 64 ----
#pragma unroll
    for (int c = 0; c < 64; ++c) acc[c] = 0.f;
#pragma unroll 2
    for (int kk = 0; kk < 64; ++kk) {
        float hv = hrow[kk];
        const float* wr = W2 + kk * 64;
#pragma unroll
        for (int c = 0; c < 64; ++c) acc[c] = fmaf(hv, wr[c], acc[c]);
    }
#pragma unroll
    for (int c = 0; c < 64; ++c)
        hrow[c] = fmaxf(fmaf(acc[c], sscale[64 + c], sbias[64 + c]), 0.f);

    // ---- layer 3: 64 -> 128 ----
    float acc3[128];
#pragma unroll
    for (int c = 0; c < 128; ++c) acc3[c] = 0.f;
#pragma unroll 2
    for (int kk = 0; kk < 64; ++kk) {
        float hv = hrow[kk];
        const float* wr = W3 + kk * 128;
#pragma unroll
        for (int c = 0; c < 128; ++c) acc3[c] = fmaf(hv, wr[c], acc3[c]);
    }
#pragma unroll
    for (int c = 0; c < 128; ++c) {
        float v = fmaxf(fmaf(acc3[c], sscale[128 + c], sbias[128 + c]), 0.f);
        acc3[c] = valid ? v : -FLT_MAX;
    }

    // ---- masked max over 32 neighbors, two 64-channel halves (reuse hbuf) ----
#pragma unroll
    for (int half = 0; half < 2; ++half) {
        __syncthreads();   // previous hbuf readers done
#pragma unroll
        for (int c = 0; c < 64; ++c) hbuf[t * 69 + c] = acc3[half * 64 + c];
        __syncthreads();
#pragma unroll
        for (int e0 = 0; e0 < 2; ++e0) {
            int e  = t + e0 * 256;          // 512 outputs per half
            int gg = e >> 6, c = e & 63;
            float mv = -FLT_MAX;
#pragma unroll
            for (int kk2 = 0; kk2 < 32; ++kk2)
                mv = fmaxf(mv, hbuf[(gg * 32 + kk2) * 69 + c]);
            out[((size_t)(cid0 + gg)) * 128 + half * 64 + c] = mv;
        }
    }
}

extern "C" void kernel_launch(void* const* d_in, const int* in_sizes, int n_in,
                              void* d_out, int out_size, void* d_ws, size_t ws_size,
                              hipStream_t stream) {
    const float* x   = (const float*)d_in[0];
    const float* pos = (const float*)d_in[1];
    const float* W1  = (const float*)d_in[2];
    const float* g1  = (const float*)d_in[3];
    const float* b1  = (const float*)d_in[4];
    const float* rm1 = (const float*)d_in[5];
    const float* rv1 = (const float*)d_in[6];
    const float* W2  = (const float*)d_in[7];
    const float* g2  = (const float*)d_in[8];
    const float* b2  = (const float*)d_in[9];
    const float* rm2 = (const float*)d_in[10];
    const float* rv2 = (const float*)d_in[11];
    const float* W3  = (const float*)d_in[12];
    const float* g3  = (const float*)d_in[13];
    const float* b3  = (const float*)d_in[14];
    const float* rm3 = (const float*)d_in[15];
    const float* rv3 = (const float*)d_in[16];

    float* out  = (float*)d_out;
    float* cpos = out + OUT_X;          // second output region
    int*   nidx = (int*)d_ws;           // B*M*K ints = 2 MiB scratch

    fps_kernel<<<dim3(BATCH), dim3(512), 0, stream>>>(pos, cpos);
    ballq_kernel<<<dim3(BATCH * MCENT / 4), dim3(256), 0, stream>>>(pos, cpos, nidx);
    mlp_kernel<<<dim3(BATCH * MCENT / 8), dim3(256), 0, stream>>>(
        x, pos, W1, g1, b1, rm1, rv1, W2, g2, b2, rm2, rv2,
        W3, g3, b3, rm3, rv3, cpos, nidx, out);
}

// Round 7
// 1120.351 us; speedup vs baseline: 1.4626x; 1.0483x over previous
//
#include <hip/hip_runtime.h>
#include <hip/hip_bf16.h>
#include <float.h>
#include <math.h>

#define BATCH 16
#define NPTS  4096
#define CIN   64
#define MCENT 1024
#define KNB   32
#define OUT_X (BATCH * MCENT * 128)

// ---- exact (non-contracted) f32 ops: bitwise-match numpy's separate roundings ----
__device__ __forceinline__ float f_sub(float a, float b){ float r; asm("v_sub_f32 %0, %1, %2" : "=v"(r) : "v"(a), "v"(b)); return r; }
__device__ __forceinline__ float f_mul(float a, float b){ float r; asm("v_mul_f32 %0, %1, %2" : "=v"(r) : "v"(a), "v"(b)); return r; }
__device__ __forceinline__ float f_add(float a, float b){ float r; asm("v_add_f32 %0, %1, %2" : "=v"(r) : "v"(a), "v"(b)); return r; }

__device__ __forceinline__ float dist2_exact(float px, float py, float pz,
                                             float lx, float ly, float lz) {
    float dx = f_sub(px, lx), dy = f_sub(py, ly), dz = f_sub(pz, lz);
    return f_add(f_add(f_mul(dx, dx), f_mul(dy, dy)), f_mul(dz, dz));
}

// fast wave-wide f32 max: 4 DPP steps + xor16 swizzle + permlane32 swap (all VALU/LDS-lite)
template <int CTRL>
__device__ __forceinline__ float dpp_max(float x) {
    int xi = __float_as_int(x);
    int yi = __builtin_amdgcn_update_dpp(xi, xi, CTRL, 0xF, 0xF, false);
    return fmaxf(x, __int_as_float(yi));
}
__device__ __forceinline__ float wave_max_f32(float v) {
    v = dpp_max<0xB1>(v);   // quad_perm [1,0,3,2]  : xor 1
    v = dpp_max<0x4E>(v);   // quad_perm [2,3,0,1]  : xor 2
    v = dpp_max<0x141>(v);  // row_half_mirror      : merge 4-groups
    v = dpp_max<0x140>(v);  // row_mirror           : merge 8-groups
    int s = __builtin_amdgcn_ds_swizzle(__float_as_int(v), 0x401F); // xor 16
    v = fmaxf(v, __int_as_float(s));
    // xor 32 via permlane32_swap (VALU, ~10cyc vs ds_bpermute ~60).
    // With a=b=v, {a,b} after swap = {v, row-swapped v} in some order; max is commutative.
    float a = v, b = v;
    asm("v_permlane32_swap_b32 %0, %1" : "+v"(a), "+v"(b));
    return fmaxf(a, b);
}

// ================= K1: farthest point sampling =================
// one block per batch; 512 threads (8 waves); each thread owns 8 contiguous points.
// One barrier per iteration: block argmax resolved by a packed-u64 LDS atomicMax
// over a 4-slot rotation (reset two-ahead keeps reset barrier-separated from
// both the last read and the next atomics of a slot).
__global__ __launch_bounds__(512, 1) void fps_kernel(
    const float* __restrict__ pos, float* __restrict__ cpos)
{
    __shared__ float spx[NPTS], spy[NPTS], spz[NPTS];
    __shared__ unsigned long long slot[4];
    __shared__ int widxarr[MCENT];

    const int b = blockIdx.x;
    const int t = threadIdx.x;
    const float* pb = pos + (size_t)b * NPTS * 3;

    float px[8], py[8], pz[8], mind[8];
    // contiguous 8 points: 6 x float4 = 96B per thread, coalesced across block
    {
        const float4* src = (const float4*)(pb + t * 24);
        float v[24];
#pragma unroll
        for (int q = 0; q < 6; ++q) {
            float4 f = src[q];
            v[q * 4 + 0] = f.x; v[q * 4 + 1] = f.y; v[q * 4 + 2] = f.z; v[q * 4 + 3] = f.w;
        }
#pragma unroll
        for (int j = 0; j < 8; ++j) {
            int n = t * 8 + j;
            px[j] = v[j * 3 + 0]; py[j] = v[j * 3 + 1]; pz[j] = v[j * 3 + 2];
            spx[n] = px[j]; spy[n] = py[j]; spz[n] = pz[j];
            mind[j] = 1e10f;
        }
    }
    if (t == 0) {
        slot[0] = 0ull; slot[1] = 0ull; slot[2] = 0ull; slot[3] = 0ull;
        widxarr[0] = 0;
    }
    __syncthreads();

    int w = 0;
    for (int i = 1; i < MCENT; ++i) {
        float lx = spx[w], ly = spy[w], lz = spz[w];
#pragma unroll
        for (int j = 0; j < 8; ++j) {
            float d = dist2_exact(px[j], py[j], pz[j], lx, ly, lz);
            mind[j] = fminf(mind[j], d);
        }
        // max3-friendly tree over the 8 mins
        float tmax = fmaxf(fmaxf(fmaxf(mind[0], mind[1]), fmaxf(mind[2], mind[3])),
                           fmaxf(fmaxf(mind[4], mind[5]), fmaxf(mind[6], mind[7])));
        float wmax = wave_max_f32(tmax);
        if (tmax == wmax) {                    // rare: ~1 lane per wave
            int cand = 0;
#pragma unroll
            for (int j = 7; j >= 0; --j)
                if (mind[j] == wmax) cand = t * 8 + j;   // ends at smallest matching j
            // key: larger dist wins; tie -> smaller index wins (argmax-first semantics)
            unsigned long long key =
                ((unsigned long long)__float_as_uint(wmax) << 32) |
                (unsigned)(NPTS - 1 - cand);
            atomicMax(&slot[i & 3], key);
        }
        if (t == 0) slot[(i + 2) & 3] = 0ull;  // reset two-ahead (barrier-separated both ways)
        __syncthreads();
        unsigned long long win = slot[i & 3];
        w = (NPTS - 1) - (int)(unsigned)(win & 0xFFFFFFFFull);
        if (t == 0) widxarr[i] = w;
    }
    __syncthreads();
    // emit centroid positions (bitwise copies of pos); 2 per thread
#pragma unroll
    for (int e = 0; e < 2; ++e) {
        int c = t + e * 512;
        int src = widxarr[c];
        float* cp = cpos + ((size_t)b * MCENT + c) * 3;
        cp[0] = spx[src]; cp[1] = spy[src]; cp[2] = spz[src];
    }
}

// ================= K2: ball query (first K in index order within radius) =================
// one wave per centroid.
__global__ __launch_bounds__(256) void ballq_kernel(
    const float* __restrict__ pos, const float* __restrict__ cpos,
    int* __restrict__ nidx)
{
    const int wid  = blockIdx.x * 4 + (threadIdx.x >> 6);  // centroid id 0..B*M-1
    const int lane = threadIdx.x & 63;
    const int b    = wid >> 10;
    const float* pb = pos + (size_t)b * NPTS * 3;
    const float cx = cpos[wid * 3 + 0];
    const float cy = cpos[wid * 3 + 1];
    const float cz = cpos[wid * 3 + 2];
    const float R2 = (float)(0.2 * 0.2);   // 0x3D23D70A — equivalent predicate to reference
    int* outp = nidx + (size_t)wid * KNB;

    int cnt = 0;
    for (int j0 = 0; j0 < NPTS; j0 += 64) {
        int j = j0 + lane;
        float x = pb[j * 3 + 0], y = pb[j * 3 + 1], z = pb[j * 3 + 2];
        float d = dist2_exact(x, y, z, cx, cy, cz);
        bool valid = (d <= R2);
        unsigned long long msk = __ballot(valid);
        if (valid) {
            int rank = cnt + __popcll(msk & ((1ull << lane) - 1ull));
            if (rank < KNB) outp[rank] = j;
        }
        cnt += __popcll(msk);
        if (cnt >= KNB) break;
    }
    int nv = cnt < KNB ? cnt : KNB;
    if (lane >= nv && lane < KNB) outp[lane] = -1;
}

// ================= K3: gather + shared MLP + masked max-pool =================
// 256 threads = 8 centroids x 32 neighbor-rows; one row per thread.
__global__ __launch_bounds__(256, 1) void mlp_kernel(
    const float* __restrict__ x, const float* __restrict__ pos,
    const float* __restrict__ W1, const float* __restrict__ g1, const float* __restrict__ b1,
    const float* __restrict__ rm1, const float* __restrict__ rv1,
    const float* __restrict__ W2, const float* __restrict__ g2, const float* __restrict__ b2,
    const float* __restrict__ rm2, const float* __restrict__ rv2,
    const float* __restrict__ W3, const float* __restrict__ g3, const float* __restrict__ b3,
    const float* __restrict__ rm3, const float* __restrict__ rv3,
    const float* __restrict__ cpos, const int* __restrict__ nidx,
    float* __restrict__ out)
{
    __shared__ float hbuf[256 * 69];      // per-thread activation row (LDS, stride 69: conflict-free)
    __shared__ float sscale[256], sbias[256];

    const int t   = threadIdx.x;
    const int g   = t >> 5;               // centroid within block
    const int k   = t & 31;               // neighbor slot
    const int cid0 = blockIdx.x * 8;
    const int cid  = cid0 + g;
    const int b    = cid >> 10;

    // fused BN(eval) constants: y = h*scale + bias
    {
        float gg, bb, rm, rv;
        if (t < 64)       { gg = g1[t];     bb = b1[t];     rm = rm1[t];     rv = rv1[t]; }
        else if (t < 128) { int c = t - 64;  gg = g2[c]; bb = b2[c]; rm = rm2[c]; rv = rv2[c]; }
        else              { int c = t - 128; gg = g3[c]; bb = b3[c]; rm = rm3[c]; rv = rv3[c]; }
        float s = gg / sqrtf(rv + 1e-5f);
        sscale[t] = s;
        sbias[t]  = bb - rm * s;
    }

    const int j = nidx[(size_t)cid * KNB + k];
    const bool valid = (j >= 0);
    float* hrow = &hbuf[t * 69];
    if (valid) {
        const float* xr = x + ((size_t)b * NPTS + j) * CIN;
#pragma unroll
        for (int q = 0; q < 16; ++q) {
            float4 v = ((const float4*)xr)[q];
            hrow[q * 4 + 0] = v.x; hrow[q * 4 + 1] = v.y;
            hrow[q * 4 + 2] = v.z; hrow[q * 4 + 3] = v.w;
        }
        const float* pr = pos + ((size_t)b * NPTS + j) * 3;
        hrow[64] = f_sub(pr[0], cpos[cid * 3 + 0]);
        hrow[65] = f_sub(pr[1], cpos[cid * 3 + 1]);
        hrow[66] = f_sub(pr[2], cpos[cid * 3 + 2]);
    } else {
        for (int q = 0; q < 67; ++q) hrow[q] = 0.f;
    }
    __syncthreads();   // sscale/sbias ready

    float acc[64];
    // ---- layer 1: 67 -> 64 ----
#pragma unroll
    for (int c = 0; c < 64; ++c) acc[c] = 0.f;
#pragma unroll 2
    for (int kk = 0; kk < 67; ++kk) {
        float hv = hrow[kk];
        const float* wr = W1 + kk * 64;     // wave-uniform -> scalar loads
#pragma unroll
        for (int c = 0; c < 64; ++c) acc[c] = fmaf(hv, wr[c], acc[c]);
    }
#pragma unroll
    for (int c = 0; c < 64; ++c)
        hrow[c] = fmaxf(fmaf(acc[c], sscale[c], sbias[c]), 0.f);

    // ---- layer 2: 64 -> 64 ----
#pragma unroll
    for (int c = 0; c < 64; ++c) acc[c] = 0.f;
#pragma unroll 2
    for (int kk = 0; kk < 64; ++kk) {
        float hv = hrow[kk];
        const float* wr = W2 + kk * 64;
#pragma unroll
        for (int c = 0; c < 64; ++c) acc[c] = fmaf(hv, wr[c], acc[c]);
    }
#pragma unroll
    for (int c = 0; c < 64; ++c)
        hrow[c] = fmaxf(fmaf(acc[c], sscale[64 + c], sbias[64 + c]), 0.f);

    // ---- layer 3: 64 -> 128 ----
    float acc3[128];
#pragma unroll
    for (int c = 0; c < 128; ++c) acc3[c] = 0.f;
#pragma unroll 2
    for (int kk = 0; kk < 64; ++kk) {
        float hv = hrow[kk];
        const float* wr = W3 + kk * 128;
#pragma unroll
        for (int c = 0; c < 128; ++c) acc3[c] = fmaf(hv, wr[c], acc3[c]);
    }
#pragma unroll
    for (int c = 0; c < 128; ++c) {
        float v = fmaxf(fmaf(acc3[c], sscale[128 + c], sbias[128 + c]), 0.f);
        acc3[c] = valid ? v : -FLT_MAX;
    }

    // ---- masked max over 32 neighbors, two 64-channel halves (reuse hbuf) ----
#pragma unroll
    for (int half = 0; half < 2; ++half) {
        __syncthreads();   // previous hbuf readers done
#pragma unroll
        for (int c = 0; c < 64; ++c) hbuf[t * 69 + c] = acc3[half * 64 + c];
        __syncthreads();
#pragma unroll
        for (int e0 = 0; e0 < 2; ++e0) {
            int e  = t + e0 * 256;          // 512 outputs per half
            int gg = e >> 6, c = e & 63;
            float mv = -FLT_MAX;
#pragma unroll
            for (int kk2 = 0; kk2 < 32; ++kk2)
                mv = fmaxf(mv, hbuf[(gg * 32 + kk2) * 69 + c]);
            out[((size_t)(cid0 + gg)) * 128 + half * 64 + c] = mv;
        }
    }
}

extern "C" void kernel_launch(void* const* d_in, const int* in_sizes, int n_in,
                              void* d_out, int out_size, void* d_ws, size_t ws_size,
                              hipStream_t stream) {
    const float* x   = (const float*)d_in[0];
    const float* pos = (const float*)d_in[1];
    const float* W1  = (const float*)d_in[2];
    const float* g1  = (const float*)d_in[3];
    const float* b1  = (const float*)d_in[4];
    const float* rm1 = (const float*)d_in[5];
    const float* rv1 = (const float*)d_in[6];
    const float* W2  = (const float*)d_in[7];
    const float* g2  = (const float*)d_in[8];
    const float* b2  = (const float*)d_in[9];
    const float* rm2 = (const float*)d_in[10];
    const float* rv2 = (const float*)d_in[11];
    const float* W3  = (const float*)d_in[12];
    const float* g3  = (const float*)d_in[13];
    const float* b3  = (const float*)d_in[14];
    const float* rm3 = (const float*)d_in[15];
    const float* rv3 = (const float*)d_in[16];

    float* out  = (float*)d_out;
    float* cpos = out + OUT_X;          // second output region
    int*   nidx = (int*)d_ws;           // B*M*K ints = 2 MiB scratch

    fps_kernel<<<dim3(BATCH), dim3(512), 0, stream>>>(pos, cpos);
    ballq_kernel<<<dim3(BATCH * MCENT / 4), dim3(256), 0, stream>>>(pos, cpos, nidx);
    mlp_kernel<<<dim3(BATCH * MCENT / 8), dim3(256), 0, stream>>>(
        x, pos, W1, g1, b1, rm1, rv1, W2, g2, b2, rm2, rv2,
        W3, g3, b3, rm3, rv3, cpos, nidx, out);
}